// Round 5
// baseline (374.815 us; speedup 1.0000x reference)
//
#include <hip/hip_runtime.h>
#include <hip/hip_bf16.h>
#include <stdint.h>

typedef __bf16 bf16_t;
typedef __attribute__((ext_vector_type(8))) __bf16 bf16x8;
typedef __attribute__((ext_vector_type(4))) __bf16 bf16x4;
typedef __attribute__((ext_vector_type(4))) float f32x4;

#define DEVI __device__ __forceinline__

DEVI void gll16(const void* g, void* lds_base_wave_uniform) {
  __builtin_amdgcn_global_load_lds(
      (const __attribute__((address_space(1))) uint32_t*)(uintptr_t)g,
      (__attribute__((address_space(3))) uint32_t*)(uintptr_t)lds_base_wave_uniform,
      16, 0, 0);
}

// ---------------- fp32 -> bf16 convert (vectorized) ----------------
__global__ void cvt_f32_to_bf16(const float* __restrict__ src, bf16_t* __restrict__ dst, int n) {
  int i = (blockIdx.x * blockDim.x + threadIdx.x) * 4;
  if (i >= n) return;
  float4 v = *(const float4*)(src + i);
  bf16x4 o = {(bf16_t)v.x, (bf16_t)v.y, (bf16_t)v.z, (bf16_t)v.w};
  *(bf16x4*)(dst + i) = o;
}

// ---------------- t-shift: shift[b][n] = dot(t[b,:256], Wt_sel[n_local,:]) -----
__global__ void shift_kernel(const float* __restrict__ t,
                             const float* __restrict__ wtq,
                             const float* __restrict__ wtk,
                             const float* __restrict__ wtv,
                             float* __restrict__ shift) {
  int idx = blockIdx.x * blockDim.x + threadIdx.x;
  if (idx >= 8 * 2304) return;
  int b = idx / 2304, n = idx % 2304;
  const float* w = (n < 768) ? (wtq + (size_t)n * 256)
                 : (n < 1536) ? (wtk + (size_t)(n - 768) * 256)
                              : (wtv + (size_t)(n - 1536) * 256);
  const float4* tv = (const float4*)(t + (size_t)b * 256);
  const float4* wv = (const float4*)w;
  float acc = 0.f;
#pragma unroll 8
  for (int i = 0; i < 64; i++) {
    float4 a = tv[i], c = wv[i];
    acc += a.x * c.x + a.y * c.y + a.z * c.z + a.w * c.w;
  }
  shift[idx] = acc;
}

// ---------------- GEMM: C[m,n] = sum_k A[m,k]*B[n,k] (+add) -------------------
template <int MODE>
__global__ __launch_bounds__(256, 2) void gemm_bt(
    const bf16_t* __restrict__ A, const bf16_t* __restrict__ B,
    const float* __restrict__ add, void* __restrict__ Cout,
    int M, int N, int K) {
  __shared__ alignas(16) bf16_t As[128 * 32];
  __shared__ alignas(16) bf16_t Bs[128 * 32];
  const int t = threadIdx.x, l = t & 63, w = t >> 6;
  const int wr = w >> 1, wc = w & 1;
  const int bm = blockIdx.x, bn = blockIdx.y;

  f32x4 acc[4][4] = {};

  const int srow = t >> 2;
  const int scol = (t & 3) * 8;
  const bf16_t* Ab = A + ((size_t)bm * 128 + srow) * K + scol;
  const bf16_t* Bb = B + ((size_t)bn * 128 + srow) * K + scol;
  char* AsB = (char*)As + w * 1024;
  char* BsB = (char*)Bs + w * 1024;
  const size_t K64 = (size_t)64 * K;

  const int ro = (l & 15) * 32 + (l >> 4) * 8;
  const bf16_t* ApA = As + (wr * 64) * 32 + ro;
  const bf16_t* BpB = Bs + (wc * 64) * 32 + ro;

  for (int k0 = 0; k0 < K; k0 += 32) {
    __syncthreads();
    gll16(Ab + k0, AsB);
    gll16(Ab + K64 + k0, AsB + 4096);
    gll16(Bb + k0, BsB);
    gll16(Bb + K64 + k0, BsB + 4096);
    __syncthreads();
    bf16x8 af[4], bfr[4];
#pragma unroll
    for (int i = 0; i < 4; i++) {
      af[i]  = *(const bf16x8*)(ApA + i * 16 * 32);
      bfr[i] = *(const bf16x8*)(BpB + i * 16 * 32);
    }
#pragma unroll
    for (int mi = 0; mi < 4; mi++)
#pragma unroll
      for (int ni = 0; ni < 4; ni++)
        acc[mi][ni] = __builtin_amdgcn_mfma_f32_16x16x32_bf16(af[mi], bfr[ni], acc[mi][ni], 0, 0, 0);
  }

  const int row0 = bm * 128 + wr * 64 + (l >> 4) * 4;
  const int col0 = bn * 128 + wc * 64 + (l & 15);
  if (MODE == 0) {
    bf16_t* C = (bf16_t*)Cout;
    const float* sh = add + (size_t)((bm * 128) >> 10) * N;
#pragma unroll
    for (int ni = 0; ni < 4; ni++) {
      const int col = col0 + ni * 16;
      const float s0 = sh[col];
#pragma unroll
      for (int mi = 0; mi < 4; mi++)
#pragma unroll
        for (int i = 0; i < 4; i++)
          C[(size_t)(row0 + mi * 16 + i) * N + col] = (bf16_t)(acc[mi][ni][i] + s0);
    }
  } else {
    float* C = (float*)Cout;
#pragma unroll
    for (int ni = 0; ni < 4; ni++) {
      const int col = col0 + ni * 16;
      const float s0 = add[col];
#pragma unroll
      for (int mi = 0; mi < 4; mi++)
#pragma unroll
        for (int i = 0; i < 4; i++)
          C[(size_t)(row0 + mi * 16 + i) * N + col] = acc[mi][ni][i] + s0;
    }
  }
}

// ---------------- fused flash attention, swapped-QK^T structure ---------------
// qkv [8][1024][2304] bf16 (q|k|v each 768 = 12 heads * 64)
// bias [12][1024][1024] fp32 ; o [8][1024][768] bf16
// Swapped QK^T: S^T = mfma(K, Q) puts a full q-row's P-slice in ONE lane ->
// softmax reduce = in-reg tree + 2 shfls (was 32 chained shfls).
__global__ __launch_bounds__(256, 4) void attn_fused(
    const bf16_t* __restrict__ qkv,
    const float* __restrict__ bias,
    bf16_t* __restrict__ o) {
  const int id = blockIdx.x;
  const int slot = id >> 3;
  const int qt = slot & 15;
  const int grp = (id & 7) + 8 * (slot >> 4);  // XCD grouping: 16 qt share an XCD
  const int h = grp % 12, b = grp / 12;
  const int t = threadIdx.x, l = t & 63, w = t >> 6;
  const int s = l & 15, g = l >> 4;

  __shared__ alignas(16) bf16_t Vt[64 * 64];
  __shared__ alignas(16) bf16_t Ps[4][16 * 64];

  const size_t rowb = (size_t)b * 1024;
  const int qrow = qt * 64 + w * 16 + s;  // softmax-layout q-row of this lane

  // Q fragments (B-operand): col = s, d = g*8+j (+32)
  bf16x8 qf[2];
  {
    const bf16_t* qp = qkv + (rowb + qrow) * 2304 + h * 64 + g * 8;
    qf[0] = *(const bf16x8*)qp;
    qf[1] = *(const bf16x8*)(qp + 32);
  }

  const bf16_t* kbase = qkv + rowb * 2304 + 768 + h * 64 + g * 8;
  const float*  bbase = bias + ((size_t)h << 20) + (size_t)qrow * 1024 + g * 4;

  float m_run = -INFINITY, l_run = 0.f;
  f32x4 oacc[4] = {};
  const float LOG2E = 1.44269504088896f;
  const float C1 = 0.125f * 1.44269504088896f;  // scale * log2(e)

  for (int kt = 0; kt < 16; kt++) {
    // ---- issue all global loads early (latency hides under barrier+compute) --
    bf16x8 kf[4][2];
    {
      const bf16_t* kb = kbase + (size_t)(kt * 64 + s) * 2304;
#pragma unroll
      for (int nf = 0; nf < 4; nf++) {
        const bf16_t* kr = kb + (size_t)(nf * 16) * 2304;
        kf[nf][0] = *(const bf16x8*)kr;
        kf[nf][1] = *(const bf16x8*)(kr + 32);
      }
    }
    f32x4 bv[4];
    {
      const float* bb = bbase + kt * 64;
#pragma unroll
      for (int nf = 0; nf < 4; nf++)
        bv[nf] = *(const f32x4*)(bb + nf * 16);
    }
    bf16x8 v0, v1;
    {
      const bf16_t* vp = qkv + (rowb + kt * 64 + l) * 2304 + 1536 + h * 64 + w * 16;
      v0 = *(const bf16x8*)vp;
      v1 = *(const bf16x8*)(vp + 8);
    }

    __syncthreads();  // previous tile's Vt reads complete
    // ---- stage V transposed (Vt[d][kp], chunk-swizzled) ----
#pragma unroll
    for (int j = 0; j < 16; j++) {
      const int d = w * 16 + j;
      const int addr = d * 64 + (((l >> 3) ^ (d & 7)) * 8) + (l & 7);
      Vt[addr] = (j < 8) ? v0[j] : v1[j - 8];
    }

    // ---- S^T = K Q^T : lane holds S[qrow][kp = 16nf + 4g + i] ----
    f32x4 sv[4];
#pragma unroll
    for (int nf = 0; nf < 4; nf++) {
      f32x4 z = {0.f, 0.f, 0.f, 0.f};
      z = __builtin_amdgcn_mfma_f32_16x16x32_bf16(kf[nf][0], qf[0], z, 0, 0, 0);
      z = __builtin_amdgcn_mfma_f32_16x16x32_bf16(kf[nf][1], qf[1], z, 0, 0, 0);
      sv[nf] = z;
    }

    // ---- logits in base-2 domain; in-lane row max ----
    float lg[4][4];
#pragma unroll
    for (int nf = 0; nf < 4; nf++)
#pragma unroll
      for (int i = 0; i < 4; i++)
        lg[nf][i] = fmaf(sv[nf][i], C1, bv[nf][i] * LOG2E);

    float mx = fmaxf(fmaxf(fmaxf(lg[0][0], lg[0][1]), fmaxf(lg[0][2], lg[0][3])),
                     fmaxf(fmaxf(lg[1][0], lg[1][1]), fmaxf(lg[1][2], lg[1][3])));
    mx = fmaxf(mx, fmaxf(fmaxf(fmaxf(lg[2][0], lg[2][1]), fmaxf(lg[2][2], lg[2][3])),
                         fmaxf(fmaxf(lg[3][0], lg[3][1]), fmaxf(lg[3][2], lg[3][3]))));
    mx = fmaxf(mx, __shfl_xor(mx, 16));
    mx = fmaxf(mx, __shfl_xor(mx, 32));

    // ---- defer-max rescale (T13): skip when growth small ----
    if (!__all(mx - m_run <= 8.0f)) {
      const float mnew = fmaxf(m_run, mx);
      const float alpha = exp2f(m_run - mnew);
      m_run = mnew;
      l_run *= alpha;
#pragma unroll
      for (int i = 0; i < 4; i++) {
        const float a_pv = __shfl(alpha, g * 4 + i);
#pragma unroll
        for (int nf2 = 0; nf2 < 4; nf2++) oacc[nf2][i] *= a_pv;
      }
    }

    // ---- exp + row sum ----
    float rs = 0.f;
#pragma unroll
    for (int nf = 0; nf < 4; nf++)
#pragma unroll
      for (int i = 0; i < 4; i++) {
        lg[nf][i] = exp2f(lg[nf][i] - m_run);
        rs += lg[nf][i];
      }
    rs += __shfl_xor(rs, 16);
    rs += __shfl_xor(rs, 32);
    l_run += rs;

    // ---- P -> per-wave LDS (packed b64, XOR-swizzled 16B chunks) ----
    // k = 16nf+4g+i lives at row s, chunk (k>>3)^(s&7), byte-in-chunk (k&7)*2
    bf16_t* Pw = Ps[w];
    {
      char* pb = (char*)Pw + s * 128 + (g & 1) * 8;
#pragma unroll
      for (int nf = 0; nf < 4; nf++) {
        bf16x4 pk = {(bf16_t)lg[nf][0], (bf16_t)lg[nf][1], (bf16_t)lg[nf][2], (bf16_t)lg[nf][3]};
        *(bf16x4*)(pb + ((2 * nf + (g >> 1)) ^ (s & 7)) * 16) = pk;
      }
    }
    // ---- P fragments for PV (A-operand: row=s, k=8g+j (+32)) ----
    bf16x8 pf[2];
#pragma unroll
    for (int c = 0; c < 2; c++)
      pf[c] = *(const bf16x8*)((char*)Pw + s * 128 + ((4 * c + g) ^ (s & 7)) * 16);

    __syncthreads();  // Vt ready

    // ---- O += P V ----
#pragma unroll
    for (int nf2 = 0; nf2 < 4; nf2++) {
      const int d = nf2 * 16 + s;
      const bf16_t* vb = Vt + d * 64;
      bf16x8 vf0 = *(const bf16x8*)(vb + ((g ^ (d & 7)) * 8));
      bf16x8 vf1 = *(const bf16x8*)(vb + (((g + 4) ^ (d & 7)) * 8));
      oacc[nf2] = __builtin_amdgcn_mfma_f32_16x16x32_bf16(pf[0], vf0, oacc[nf2], 0, 0, 0);
      oacc[nf2] = __builtin_amdgcn_mfma_f32_16x16x32_bf16(pf[1], vf1, oacc[nf2], 0, 0, 0);
    }
  }

  // ---- normalize + store (C-layout: row q = g*4+i, col d = nf2*16+s) ----
#pragma unroll
  for (int i = 0; i < 4; i++) {
    const float inv = 1.0f / __shfl(l_run, g * 4 + i);
    const size_t row = rowb + qt * 64 + w * 16 + g * 4 + i;
#pragma unroll
    for (int nf2 = 0; nf2 < 4; nf2++)
      o[row * 768 + h * 64 + nf2 * 16 + s] = (bf16_t)(oacc[nf2][i] * inv);
  }
}

// ------------------------------- launcher ------------------------------------
extern "C" void kernel_launch(void* const* d_in, const int* in_sizes, int n_in,
                              void* d_out, int out_size, void* d_ws, size_t ws_size,
                              hipStream_t stream) {
  const float* x    = (const float*)d_in[0];
  const float* tin  = (const float*)d_in[1];
  const float* bias = (const float*)d_in[2];
  const float* Wxq  = (const float*)d_in[3];
  const float* Wxk  = (const float*)d_in[4];
  const float* Wxv  = (const float*)d_in[5];
  const float* Wtq  = (const float*)d_in[6];
  const float* Wtk  = (const float*)d_in[7];
  const float* Wtv  = (const float*)d_in[8];
  const float* Wo   = (const float*)d_in[9];
  const float* bo   = (const float*)d_in[10];
  float* out = (float*)d_out;

  char* ws = (char*)d_ws;
  bf16_t* x_bf    = (bf16_t*)(ws);                 // 12,582,912
  bf16_t* wcat    = (bf16_t*)(ws + 12582912);      //  3,538,944
  bf16_t* wo_bf   = (bf16_t*)(ws + 16121856);      //  1,179,648
  float*  shift   = (float*) (ws + 17301504);      //     73,728
  bf16_t* qkvb    = (bf16_t*)(ws + 17375232);      // 37,748,736
  bf16_t* obuf    = (bf16_t*)(ws + 55123968);      // 12,582,912
  // total 67,706,880 bytes

  const int W = 768 * 768;
  cvt_f32_to_bf16<<<6144, 256, 0, stream>>>(x, x_bf, 8192 * 768);
  cvt_f32_to_bf16<<<576, 256, 0, stream>>>(Wxq, wcat, W);
  cvt_f32_to_bf16<<<576, 256, 0, stream>>>(Wxk, wcat + W, W);
  cvt_f32_to_bf16<<<576, 256, 0, stream>>>(Wxv, wcat + 2 * W, W);
  cvt_f32_to_bf16<<<576, 256, 0, stream>>>(Wo, wo_bf, W);
  shift_kernel<<<72, 256, 0, stream>>>(tin, Wtq, Wtk, Wtv, shift);
  gemm_bt<0><<<dim3(64, 18), 256, 0, stream>>>(x_bf, wcat, shift, qkvb, 8192, 2304, 768);
  attn_fused<<<1536, 256, 0, stream>>>(qkvb, bias, obuf);
  gemm_bt<1><<<dim3(64, 6), 256, 0, stream>>>(obuf, wo_bf, bo, out, 8192, 768, 768);
}

// Round 7
// 316.276 us; speedup vs baseline: 1.1851x; 1.1851x over previous
//
#include <hip/hip_runtime.h>
#include <hip/hip_bf16.h>
#include <stdint.h>

typedef __bf16 bf16_t;
typedef __attribute__((ext_vector_type(8))) __bf16 bf16x8;
typedef __attribute__((ext_vector_type(4))) __bf16 bf16x4;
typedef __attribute__((ext_vector_type(4))) float f32x4;

#define DEVI __device__ __forceinline__

DEVI void gll16(const void* g, void* lds_base_wave_uniform) {
  __builtin_amdgcn_global_load_lds(
      (const __attribute__((address_space(1))) uint32_t*)(uintptr_t)g,
      (__attribute__((address_space(3))) uint32_t*)(uintptr_t)lds_base_wave_uniform,
      16, 0, 0);
}

// ---------------- fp32 -> bf16 convert (vectorized) ----------------
__global__ void cvt_f32_to_bf16(const float* __restrict__ src, bf16_t* __restrict__ dst, int n) {
  int i = (blockIdx.x * blockDim.x + threadIdx.x) * 4;
  if (i >= n) return;
  float4 v = *(const float4*)(src + i);
  bf16x4 o = {(bf16_t)v.x, (bf16_t)v.y, (bf16_t)v.z, (bf16_t)v.w};
  *(bf16x4*)(dst + i) = o;
}

// fp32 -> bf16 with pre-scale by log2(e) (bias enters base-2 softmax directly)
__global__ void cvt_scale_bf16(const float* __restrict__ src, bf16_t* __restrict__ dst, int n) {
  int i = (blockIdx.x * blockDim.x + threadIdx.x) * 4;
  if (i >= n) return;
  const float s = 1.44269504088896f;
  float4 v = *(const float4*)(src + i);
  bf16x4 o = {(bf16_t)(v.x * s), (bf16_t)(v.y * s), (bf16_t)(v.z * s), (bf16_t)(v.w * s)};
  *(bf16x4*)(dst + i) = o;
}

// ---------------- t-shift: shift[b][n] = dot(t[b,:256], Wt_sel[n_local,:]) -----
__global__ void shift_kernel(const float* __restrict__ t,
                             const float* __restrict__ wtq,
                             const float* __restrict__ wtk,
                             const float* __restrict__ wtv,
                             float* __restrict__ shift) {
  int idx = blockIdx.x * blockDim.x + threadIdx.x;
  if (idx >= 8 * 2304) return;
  int b = idx / 2304, n = idx % 2304;
  const float* w = (n < 768) ? (wtq + (size_t)n * 256)
                 : (n < 1536) ? (wtk + (size_t)(n - 768) * 256)
                              : (wtv + (size_t)(n - 1536) * 256);
  const float4* tv = (const float4*)(t + (size_t)b * 256);
  const float4* wv = (const float4*)w;
  float acc = 0.f;
#pragma unroll 8
  for (int i = 0; i < 64; i++) {
    float4 a = tv[i], c = wv[i];
    acc += a.x * c.x + a.y * c.y + a.z * c.z + a.w * c.w;
  }
  shift[idx] = acc;
}

// ---------------- GEMM: C[m,n] = sum_k A[m,k]*B[n,k] (+add) -------------------
template <int MODE>
__global__ __launch_bounds__(256, 2) void gemm_bt(
    const bf16_t* __restrict__ A, const bf16_t* __restrict__ B,
    const float* __restrict__ add, void* __restrict__ Cout,
    int M, int N, int K) {
  __shared__ alignas(16) bf16_t As[128 * 32];
  __shared__ alignas(16) bf16_t Bs[128 * 32];
  const int t = threadIdx.x, l = t & 63, w = t >> 6;
  const int wr = w >> 1, wc = w & 1;
  const int bm = blockIdx.x, bn = blockIdx.y;

  f32x4 acc[4][4] = {};

  const int srow = t >> 2;
  const int scol = (t & 3) * 8;
  const bf16_t* Ab = A + ((size_t)bm * 128 + srow) * K + scol;
  const bf16_t* Bb = B + ((size_t)bn * 128 + srow) * K + scol;
  char* AsB = (char*)As + w * 1024;
  char* BsB = (char*)Bs + w * 1024;
  const size_t K64 = (size_t)64 * K;

  const int ro = (l & 15) * 32 + (l >> 4) * 8;
  const bf16_t* ApA = As + (wr * 64) * 32 + ro;
  const bf16_t* BpB = Bs + (wc * 64) * 32 + ro;

  for (int k0 = 0; k0 < K; k0 += 32) {
    __syncthreads();
    gll16(Ab + k0, AsB);
    gll16(Ab + K64 + k0, AsB + 4096);
    gll16(Bb + k0, BsB);
    gll16(Bb + K64 + k0, BsB + 4096);
    __syncthreads();
    bf16x8 af[4], bfr[4];
#pragma unroll
    for (int i = 0; i < 4; i++) {
      af[i]  = *(const bf16x8*)(ApA + i * 16 * 32);
      bfr[i] = *(const bf16x8*)(BpB + i * 16 * 32);
    }
#pragma unroll
    for (int mi = 0; mi < 4; mi++)
#pragma unroll
      for (int ni = 0; ni < 4; ni++)
        acc[mi][ni] = __builtin_amdgcn_mfma_f32_16x16x32_bf16(af[mi], bfr[ni], acc[mi][ni], 0, 0, 0);
  }

  const int row0 = bm * 128 + wr * 64 + (l >> 4) * 4;
  const int col0 = bn * 128 + wc * 64 + (l & 15);
  if (MODE == 0) {
    bf16_t* C = (bf16_t*)Cout;
    const float* sh = add + (size_t)((bm * 128) >> 10) * N;
#pragma unroll
    for (int ni = 0; ni < 4; ni++) {
      const int col = col0 + ni * 16;
      const float s0 = sh[col];
#pragma unroll
      for (int mi = 0; mi < 4; mi++)
#pragma unroll
        for (int i = 0; i < 4; i++)
          C[(size_t)(row0 + mi * 16 + i) * N + col] = (bf16_t)(acc[mi][ni][i] + s0);
    }
  } else {
    float* C = (float*)Cout;
#pragma unroll
    for (int ni = 0; ni < 4; ni++) {
      const int col = col0 + ni * 16;
      const float s0 = add[col];
#pragma unroll
      for (int mi = 0; mi < 4; mi++)
#pragma unroll
        for (int i = 0; i < 4; i++)
          C[(size_t)(row0 + mi * 16 + i) * N + col] = acc[mi][ni][i] + s0;
    }
  }
}

// ---------------- fused flash attention: swapped softmax + async pipeline -----
// qkv [8][1024][2304] bf16; biasb [12][1024][1024] bf16 (pre-scaled by log2e)
// o [8][1024][768] bf16
// Per tile: gll16-stage K & bias (double-buffered, counted vmcnt(2) so DMA of
// tile kt+1 stays in flight across the barrier), reg-stage V (2 tiles ahead),
// swapped QK^T (full P-row per lane -> 2-shfl softmax), defer-max rescale.
__global__ __launch_bounds__(256, 2) void attn_fused(
    const bf16_t* __restrict__ qkv,
    const bf16_t* __restrict__ biasb,
    bf16_t* __restrict__ o) {
  const int id = blockIdx.x;
  const int slot = id >> 3;
  const int qt = slot & 15;
  const int grp = (id & 7) + 8 * (slot >> 4);  // 16 qt of one (h,b) share an XCD
  const int h = grp % 12, b = grp / 12;
  const int t = threadIdx.x, l = t & 63, w = t >> 6;
  const int sl = l & 15, g = l >> 4;

  __shared__ alignas(16) bf16_t Ks[2][64 * 64];
  __shared__ alignas(16) bf16_t Bi[2][64 * 64];
  __shared__ alignas(16) bf16_t Vt[2][64 * 64];
  __shared__ alignas(16) bf16_t Ps[4][16 * 64];

  const size_t rowb = (size_t)b * 1024;
  const int qrow = qt * 64 + w * 16 + sl;

  // Q fragment (B-operand): col=sl, k=8g+j (+32)
  bf16x8 qf[2];
  {
    const bf16_t* qp = qkv + (rowb + qrow) * 2304 + h * 64 + g * 8;
    qf[0] = *(const bf16x8*)qp;
    qf[1] = *(const bf16x8*)(qp + 32);
  }
  __builtin_amdgcn_sched_barrier(0);  // pin q-loads first in the vmem queue

  // staging geometry: wave w covers tile rows w*16..w*16+15 (two 1KB issues);
  // lane covers row w*16+ii*8+(l>>3), chunk l&7; row&7 == l>>3 for all ii,w.
  const int st_row = w * 16 + (l >> 3);
  const int st_chk = (l & 7) ^ (l >> 3);  // inverse-swizzled source chunk
  const bf16_t* ksrc = qkv + rowb * 2304 + 768 + h * 64;
  const bf16_t* bsrc = biasb + ((size_t)h << 20) + (size_t)(qt * 64) * 1024;

  auto STAGE = [&](int buf, int kt2) {
    const bf16_t* k0 = ksrc + (size_t)(kt2 * 64 + st_row) * 2304 + st_chk * 8;
    gll16(k0,            (char*)Ks[buf] + w * 2048);
    gll16(k0 + 8 * 2304, (char*)Ks[buf] + w * 2048 + 1024);
    const bf16_t* b0 = bsrc + (size_t)st_row * 1024 + kt2 * 64 + st_chk * 8;
    gll16(b0,            (char*)Bi[buf] + w * 2048);
    gll16(b0 + 8 * 1024, (char*)Bi[buf] + w * 2048 + 1024);
  };
  auto VLOAD = [&](int kt2, bf16x8& a, bf16x8& bq) {
    const bf16_t* vp = qkv + (rowb + kt2 * 64 + l) * 2304 + 1536 + h * 64 + w * 16;
    a = *(const bf16x8*)vp;
    bq = *(const bf16x8*)(vp + 8);
  };
  auto VSCAT = [&](int buf, const bf16x8& a, const bf16x8& bq) {
#pragma unroll
    for (int j = 0; j < 16; j++) {
      const int d = w * 16 + j;
      const int addr = d * 64 + (((l >> 3) ^ (d & 7)) * 8) + (l & 7);
      Vt[buf][addr] = (j < 8) ? a[j] : bq[j - 8];
    }
  };

  float m_run = -INFINITY, l_run = 0.f;
  f32x4 oacc[4] = {};
  const float C1 = 0.125f * 1.44269504088896f;  // scale * log2(e)

  bf16x8 va0, va1, vb0, vb1;

  // ---- prologue: V(0), stage(0), V(1); scatter V(0); drain stage(0) ----
  VLOAD(0, va0, va1);
  __builtin_amdgcn_sched_barrier(0);
  STAGE(0, 0);
  __builtin_amdgcn_sched_barrier(0);
  VLOAD(1, vb0, vb1);
  __builtin_amdgcn_sched_barrier(0);
  VSCAT(0, va0, va1);  // compiler auto-waits va's vmcnt
  asm volatile("s_waitcnt vmcnt(2) lgkmcnt(0)" ::: "memory");  // stage(0) landed; V(1) in flight
  __builtin_amdgcn_s_barrier();
  __builtin_amdgcn_sched_barrier(0);

#pragma unroll 2
  for (int kt = 0; kt < 16; kt++) {
    const int cur = kt & 1, nxt = cur ^ 1;

    // ---- issue next-tile work (order pinned: stage, then V-load) ----
    if (kt + 1 < 16) {
      STAGE(nxt, kt + 1);
      __builtin_amdgcn_sched_barrier(0);
    }
    if (kt + 2 < 16) {
      if (cur == 0) VLOAD(kt + 2, va0, va1);
      else          VLOAD(kt + 2, vb0, vb1);
      __builtin_amdgcn_sched_barrier(0);
    }
    if (kt + 1 < 16) {
      if (cur == 0) VSCAT(nxt, vb0, vb1);  // V(kt+1), loaded last iter
      else          VSCAT(nxt, va0, va1);
    }

    // ---- S^T = K Q^T : lane holds S[qrow][kp = 16nf + 4g + i] ----
    f32x4 sv[4];
    __builtin_amdgcn_s_setprio(1);
#pragma unroll
    for (int nf = 0; nf < 4; nf++) {
      const char* base = (const char*)Ks[cur] + (16 * nf + sl) * 128;
      bf16x8 kf0 = *(const bf16x8*)(base + ((g ^ (sl & 7)) * 16));
      bf16x8 kf1 = *(const bf16x8*)(base + (((4 + g) ^ (sl & 7)) * 16));
      f32x4 z = {0.f, 0.f, 0.f, 0.f};
      z = __builtin_amdgcn_mfma_f32_16x16x32_bf16(kf0, qf[0], z, 0, 0, 0);
      z = __builtin_amdgcn_mfma_f32_16x16x32_bf16(kf1, qf[1], z, 0, 0, 0);
      sv[nf] = z;
    }
    __builtin_amdgcn_s_setprio(0);

    // ---- bias (bf16, pre-scaled by log2e) in C-fragment layout ----
    float lg[4][4];
    {
      const char* bb = (const char*)Bi[cur] + (w * 16 + sl) * 128 + (g & 1) * 8;
#pragma unroll
      for (int nf = 0; nf < 4; nf++) {
        bf16x4 bq = *(const bf16x4*)(bb + (((2 * nf + (g >> 1)) ^ (sl & 7)) * 16));
#pragma unroll
        for (int i = 0; i < 4; i++)
          lg[nf][i] = fmaf(sv[nf][i], C1, (float)bq[i]);
      }
    }

    // ---- row max: in-reg tree + 2 shfls ----
    float mx = fmaxf(fmaxf(fmaxf(lg[0][0], lg[0][1]), fmaxf(lg[0][2], lg[0][3])),
                     fmaxf(fmaxf(lg[1][0], lg[1][1]), fmaxf(lg[1][2], lg[1][3])));
    mx = fmaxf(mx, fmaxf(fmaxf(fmaxf(lg[2][0], lg[2][1]), fmaxf(lg[2][2], lg[2][3])),
                         fmaxf(fmaxf(lg[3][0], lg[3][1]), fmaxf(lg[3][2], lg[3][3]))));
    mx = fmaxf(mx, __shfl_xor(mx, 16));
    mx = fmaxf(mx, __shfl_xor(mx, 32));

    // ---- defer-max rescale (T13) ----
    if (!__all(mx - m_run <= 8.0f)) {
      const float mnew = fmaxf(m_run, mx);
      const float alpha = exp2f(m_run - mnew);
      m_run = mnew;
      l_run *= alpha;
#pragma unroll
      for (int i = 0; i < 4; i++) {
        const float a_pv = __shfl(alpha, g * 4 + i);
#pragma unroll
        for (int nf2 = 0; nf2 < 4; nf2++) oacc[nf2][i] *= a_pv;
      }
    }

    // ---- exp + row sum ----
    float rs = 0.f;
#pragma unroll
    for (int nf = 0; nf < 4; nf++)
#pragma unroll
      for (int i = 0; i < 4; i++) {
        lg[nf][i] = exp2f(lg[nf][i] - m_run);
        rs += lg[nf][i];
      }
    rs += __shfl_xor(rs, 16);
    rs += __shfl_xor(rs, 32);
    l_run += rs;

    // ---- P -> per-wave LDS (packed b64, XOR-swizzled) ----
    bf16_t* Pw = Ps[w];
    {
      char* pb = (char*)Pw + sl * 128 + (g & 1) * 8;
#pragma unroll
      for (int nf = 0; nf < 4; nf++) {
        bf16x4 pk = {(bf16_t)lg[nf][0], (bf16_t)lg[nf][1], (bf16_t)lg[nf][2], (bf16_t)lg[nf][3]};
        *(bf16x4*)(pb + ((2 * nf + (g >> 1)) ^ (sl & 7)) * 16) = pk;
      }
    }
    bf16x8 pf[2];
#pragma unroll
    for (int c = 0; c < 2; c++)
      pf[c] = *(const bf16x8*)((char*)Pw + sl * 128 + ((4 * c + g) ^ (sl & 7)) * 16);

    // ---- O += P V ----
    __builtin_amdgcn_s_setprio(1);
#pragma unroll
    for (int nf2 = 0; nf2 < 4; nf2++) {
      const int d = nf2 * 16 + sl;
      const bf16_t* vb = Vt[cur] + d * 64;
      bf16x8 vf0 = *(const bf16x8*)(vb + ((g ^ (d & 7)) * 8));
      bf16x8 vf1 = *(const bf16x8*)(vb + (((g + 4) ^ (d & 7)) * 8));
      oacc[nf2] = __builtin_amdgcn_mfma_f32_16x16x32_bf16(pf[0], vf0, oacc[nf2], 0, 0, 0);
      oacc[nf2] = __builtin_amdgcn_mfma_f32_16x16x32_bf16(pf[1], vf1, oacc[nf2], 0, 0, 0);
    }
    __builtin_amdgcn_s_setprio(0);

    // ---- tile boundary: counted vmcnt keeps next-tile DMA in flight ----
    if (kt + 1 < 16) {
      if (kt + 2 < 16) asm volatile("s_waitcnt vmcnt(2) lgkmcnt(0)" ::: "memory");
      else             asm volatile("s_waitcnt vmcnt(0) lgkmcnt(0)" ::: "memory");
      __builtin_amdgcn_s_barrier();
      __builtin_amdgcn_sched_barrier(0);
    }
  }

  // ---- normalize + store (C-layout: row q = g*4+i, col d = nf2*16+sl) ----
#pragma unroll
  for (int i = 0; i < 4; i++) {
    const float inv = 1.0f / __shfl(l_run, g * 4 + i);
    const size_t row = rowb + qt * 64 + w * 16 + g * 4 + i;
#pragma unroll
    for (int nf2 = 0; nf2 < 4; nf2++)
      o[row * 768 + h * 64 + nf2 * 16 + sl] = (bf16_t)(oacc[nf2][i] * inv);
  }
}

// ------------------------------- launcher ------------------------------------
extern "C" void kernel_launch(void* const* d_in, const int* in_sizes, int n_in,
                              void* d_out, int out_size, void* d_ws, size_t ws_size,
                              hipStream_t stream) {
  const float* x    = (const float*)d_in[0];
  const float* tin  = (const float*)d_in[1];
  const float* bias = (const float*)d_in[2];
  const float* Wxq  = (const float*)d_in[3];
  const float* Wxk  = (const float*)d_in[4];
  const float* Wxv  = (const float*)d_in[5];
  const float* Wtq  = (const float*)d_in[6];
  const float* Wtk  = (const float*)d_in[7];
  const float* Wtv  = (const float*)d_in[8];
  const float* Wo   = (const float*)d_in[9];
  const float* bo   = (const float*)d_in[10];
  float* out = (float*)d_out;

  char* ws = (char*)d_ws;
  bf16_t* x_bf    = (bf16_t*)(ws);                 // 12,582,912
  bf16_t* wcat    = (bf16_t*)(ws + 12582912);      //  3,538,944
  bf16_t* wo_bf   = (bf16_t*)(ws + 16121856);      //  1,179,648
  float*  shift   = (float*) (ws + 17301504);      //     73,728
  bf16_t* qkvb    = (bf16_t*)(ws + 17375232);      // 37,748,736
  bf16_t* obuf    = (bf16_t*)(ws + 55123968);      // 12,582,912
  bf16_t* bias_bf = (bf16_t*)(ws + 67706880);      // 25,165,824
  // total 92,872,704 bytes

  const int W = 768 * 768;
  cvt_f32_to_bf16<<<6144, 256, 0, stream>>>(x, x_bf, 8192 * 768);
  cvt_f32_to_bf16<<<576, 256, 0, stream>>>(Wxq, wcat, W);
  cvt_f32_to_bf16<<<576, 256, 0, stream>>>(Wxk, wcat + W, W);
  cvt_f32_to_bf16<<<576, 256, 0, stream>>>(Wxv, wcat + 2 * W, W);
  cvt_f32_to_bf16<<<576, 256, 0, stream>>>(Wo, wo_bf, W);
  cvt_scale_bf16<<<12288, 256, 0, stream>>>(bias, bias_bf, 12 * 1024 * 1024);
  shift_kernel<<<72, 256, 0, stream>>>(tin, Wtq, Wtk, Wtv, shift);
  gemm_bt<0><<<dim3(64, 18), 256, 0, stream>>>(x_bf, wcat, shift, qkvb, 8192, 2304, 768);
  attn_fused<<<1536, 256, 0, stream>>>(qkvb, bias_bf, obuf);
  gemm_bt<1><<<dim3(64, 6), 256, 0, stream>>>(obuf, wo_bf, bo, out, 8192, 768, 768);
}

// Round 9
// 303.094 us; speedup vs baseline: 1.2366x; 1.0435x over previous
//
#include <hip/hip_runtime.h>
#include <hip/hip_bf16.h>
#include <stdint.h>

typedef __bf16 bf16_t;
typedef __attribute__((ext_vector_type(8))) __bf16 bf16x8;
typedef __attribute__((ext_vector_type(4))) __bf16 bf16x4;
typedef __attribute__((ext_vector_type(4))) float f32x4;

#define DEVI __device__ __forceinline__

DEVI void gll16(const void* g, void* lds_base_wave_uniform) {
  __builtin_amdgcn_global_load_lds(
      (const __attribute__((address_space(1))) uint32_t*)(uintptr_t)g,
      (__attribute__((address_space(3))) uint32_t*)(uintptr_t)lds_base_wave_uniform,
      16, 0, 0);
}

// ---------------- fp32 -> bf16 convert (vectorized) ----------------
__global__ void cvt_f32_to_bf16(const float* __restrict__ src, bf16_t* __restrict__ dst, int n) {
  int i = (blockIdx.x * blockDim.x + threadIdx.x) * 4;
  if (i >= n) return;
  float4 v = *(const float4*)(src + i);
  bf16x4 o = {(bf16_t)v.x, (bf16_t)v.y, (bf16_t)v.z, (bf16_t)v.w};
  *(bf16x4*)(dst + i) = o;
}

// fp32 -> bf16 with pre-scale by log2(e) (bias enters base-2 softmax directly)
__global__ void cvt_scale_bf16(const float* __restrict__ src, bf16_t* __restrict__ dst, int n) {
  int i = (blockIdx.x * blockDim.x + threadIdx.x) * 4;
  if (i >= n) return;
  const float s = 1.44269504088896f;
  float4 v = *(const float4*)(src + i);
  bf16x4 o = {(bf16_t)(v.x * s), (bf16_t)(v.y * s), (bf16_t)(v.z * s), (bf16_t)(v.w * s)};
  *(bf16x4*)(dst + i) = o;
}

// ---------------- t-shift: shift[b][n] = dot(t[b,:256], Wt_sel[n_local,:]) -----
__global__ void shift_kernel(const float* __restrict__ t,
                             const float* __restrict__ wtq,
                             const float* __restrict__ wtk,
                             const float* __restrict__ wtv,
                             float* __restrict__ shift) {
  int idx = blockIdx.x * blockDim.x + threadIdx.x;
  if (idx >= 8 * 2304) return;
  int b = idx / 2304, n = idx % 2304;
  const float* w = (n < 768) ? (wtq + (size_t)n * 256)
                 : (n < 1536) ? (wtk + (size_t)(n - 768) * 256)
                              : (wtv + (size_t)(n - 1536) * 256);
  const float4* tv = (const float4*)(t + (size_t)b * 256);
  const float4* wv = (const float4*)w;
  float acc = 0.f;
#pragma unroll 8
  for (int i = 0; i < 64; i++) {
    float4 a = tv[i], c = wv[i];
    acc += a.x * c.x + a.y * c.y + a.z * c.z + a.w * c.w;
  }
  shift[idx] = acc;
}

// ---------------- GEMM: C[m,n] = sum_k A[m,k]*B[n,k] (+add) -------------------
// 2-phase pipeline (T3-min): STAGE(t+1) issued BEFORE compute(t); one
// vmcnt(0)+barrier per K-tile so the DMA overlaps ds_read+MFMA.
template <int MODE>
__global__ __launch_bounds__(256, 2) void gemm_bt(
    const bf16_t* __restrict__ A, const bf16_t* __restrict__ B,
    const float* __restrict__ add, void* __restrict__ Cout,
    int M, int N, int K) {
  __shared__ alignas(16) bf16_t As[2][128 * 32];
  __shared__ alignas(16) bf16_t Bs[2][128 * 32];
  const int t = threadIdx.x, l = t & 63, w = t >> 6;
  const int wr = w >> 1, wc = w & 1;
  const int bm = blockIdx.x, bn = blockIdx.y;

  f32x4 acc[4][4] = {};

  const int srow = t >> 2;
  const int scol = (t & 3) * 8;
  const bf16_t* Ab = A + ((size_t)bm * 128 + srow) * K + scol;
  const bf16_t* Bb = B + ((size_t)bn * 128 + srow) * K + scol;
  const size_t K64 = (size_t)64 * K;

  auto STAGE = [&](int buf, int k0) {
    char* AsB = (char*)As[buf] + w * 1024;
    char* BsB = (char*)Bs[buf] + w * 1024;
    gll16(Ab + k0, AsB);
    gll16(Ab + K64 + k0, AsB + 4096);
    gll16(Bb + k0, BsB);
    gll16(Bb + K64 + k0, BsB + 4096);
  };

  const int ro = (l & 15) * 32 + (l >> 4) * 8;
  const int NT = K / 32;

  STAGE(0, 0);
  asm volatile("s_waitcnt vmcnt(0)" ::: "memory");
  __builtin_amdgcn_s_barrier();
  __builtin_amdgcn_sched_barrier(0);

  for (int tt = 0; tt < NT; tt++) {
    const int cur = tt & 1;
    if (tt + 1 < NT) {
      STAGE(cur ^ 1, (tt + 1) * 32);
      __builtin_amdgcn_sched_barrier(0);
    }
    const bf16_t* Ap = As[cur] + (wr * 64) * 32 + ro;
    const bf16_t* Bp = Bs[cur] + (wc * 64) * 32 + ro;
    bf16x8 af[4], bfr[4];
#pragma unroll
    for (int i = 0; i < 4; i++) {
      af[i]  = *(const bf16x8*)(Ap + i * 16 * 32);
      bfr[i] = *(const bf16x8*)(Bp + i * 16 * 32);
    }
#pragma unroll
    for (int mi = 0; mi < 4; mi++)
#pragma unroll
      for (int ni = 0; ni < 4; ni++)
        acc[mi][ni] = __builtin_amdgcn_mfma_f32_16x16x32_bf16(af[mi], bfr[ni], acc[mi][ni], 0, 0, 0);
    if (tt + 1 < NT) {
      asm volatile("s_waitcnt vmcnt(0) lgkmcnt(0)" ::: "memory");
      __builtin_amdgcn_s_barrier();
      __builtin_amdgcn_sched_barrier(0);
    }
  }

  const int row0 = bm * 128 + wr * 64 + (l >> 4) * 4;
  const int col0 = bn * 128 + wc * 64 + (l & 15);
  if (MODE == 0) {
    bf16_t* C = (bf16_t*)Cout;
    const float* sh = add + (size_t)((bm * 128) >> 10) * N;
#pragma unroll
    for (int ni = 0; ni < 4; ni++) {
      const int col = col0 + ni * 16;
      const float s0 = sh[col];
#pragma unroll
      for (int mi = 0; mi < 4; mi++)
#pragma unroll
        for (int i = 0; i < 4; i++)
          C[(size_t)(row0 + mi * 16 + i) * N + col] = (bf16_t)(acc[mi][ni][i] + s0);
    }
  } else {
    float* C = (float*)Cout;
#pragma unroll
    for (int ni = 0; ni < 4; ni++) {
      const int col = col0 + ni * 16;
      const float s0 = add[col];
#pragma unroll
      for (int mi = 0; mi < 4; mi++)
#pragma unroll
        for (int i = 0; i < 4; i++)
          C[(size_t)(row0 + mi * 16 + i) * N + col] = acc[mi][ni][i] + s0;
    }
  }
}

// ---------------- fused flash attention: swapped softmax + async pipeline -----
// qkv [8][1024][2304] bf16; biasb [12][1024][1024] bf16 (pre-scaled by log2e)
// o [8][1024][768] bf16
// LDS 40KB (K dbuf + V dbuf + P) -> 4 blocks/CU. Bias loads go straight into
// C-fragment registers (bf16x4, lane-local rows under the swapped layout),
// prefetched one tile ahead. Counted vmcnt keeps K-DMA of tile kt+1 in flight.
__global__ __launch_bounds__(256, 4) void attn_fused(
    const bf16_t* __restrict__ qkv,
    const bf16_t* __restrict__ biasb,
    bf16_t* __restrict__ o) {
  const int id = blockIdx.x;
  const int slot = id >> 3;
  const int qt = slot & 15;
  const int grp = (id & 7) + 8 * (slot >> 4);  // 16 qt of one (h,b) share an XCD
  const int h = grp % 12, b = grp / 12;
  const int t = threadIdx.x, l = t & 63, w = t >> 6;
  const int sl = l & 15, g = l >> 4;

  __shared__ alignas(16) bf16_t Ks[2][64 * 64];
  __shared__ alignas(16) bf16_t Vt[2][64 * 64];
  __shared__ alignas(16) bf16_t Ps[4][16 * 64];

  const size_t rowb = (size_t)b * 1024;
  const int qrow = qt * 64 + w * 16 + sl;

  // Q fragment (B-operand): col=sl, k=8g+j (+32)
  bf16x8 qf[2];
  {
    const bf16_t* qp = qkv + (rowb + qrow) * 2304 + h * 64 + g * 8;
    qf[0] = *(const bf16x8*)qp;
    qf[1] = *(const bf16x8*)(qp + 32);
  }
  __builtin_amdgcn_sched_barrier(0);

  const int st_row = w * 16 + (l >> 3);
  const int st_chk = (l & 7) ^ (l >> 3);
  const bf16_t* ksrc = qkv + rowb * 2304 + 768 + h * 64;
  const bf16_t* bsrc = biasb + ((size_t)h << 20) + (size_t)qrow * 1024 + g * 4;

  auto STAGEK = [&](int buf, int kt2) {
    const bf16_t* k0 = ksrc + (size_t)(kt2 * 64 + st_row) * 2304 + st_chk * 8;
    gll16(k0,            (char*)Ks[buf] + w * 2048);
    gll16(k0 + 8 * 2304, (char*)Ks[buf] + w * 2048 + 1024);
  };
  auto VLOAD = [&](int kt2, bf16x8& a, bf16x8& bq) {
    const bf16_t* vp = qkv + (rowb + kt2 * 64 + l) * 2304 + 1536 + h * 64 + w * 16;
    a = *(const bf16x8*)vp;
    bq = *(const bf16x8*)(vp + 8);
  };
  auto VSCAT = [&](int buf, const bf16x8& a, const bf16x8& bq) {
#pragma unroll
    for (int j = 0; j < 16; j++) {
      const int d = w * 16 + j;
      const int addr = d * 64 + (((l >> 3) ^ (d & 7)) * 8) + (l & 7);
      Vt[buf][addr] = (j < 8) ? a[j] : bq[j - 8];
    }
  };

  float m_run = -INFINITY, l_run = 0.f;
  f32x4 oacc[4] = {};
  const float C1 = 0.125f * 1.44269504088896f;  // scale * log2(e)

  bf16x8 va0, va1, vb0, vb1;
  bf16x4 biasA[4], biasB[4];

  // ---- prologue: V(0), K(0), bias(0), V(1); scatter V(0); drain K(0) ----
  VLOAD(0, va0, va1);
  __builtin_amdgcn_sched_barrier(0);
  STAGEK(0, 0);
  __builtin_amdgcn_sched_barrier(0);
  {
    const bf16_t* bb = bsrc;
#pragma unroll
    for (int nf = 0; nf < 4; nf++) biasA[nf] = *(const bf16x4*)(bb + nf * 16);
  }
  __builtin_amdgcn_sched_barrier(0);
  VLOAD(1, vb0, vb1);
  __builtin_amdgcn_sched_barrier(0);
  VSCAT(0, va0, va1);  // dep-waits V(0)
  asm volatile("s_waitcnt vmcnt(6) lgkmcnt(0)" ::: "memory");  // K(0) landed; bias+V(1) in flight
  __builtin_amdgcn_s_barrier();
  __builtin_amdgcn_sched_barrier(0);

#pragma unroll 2
  for (int kt = 0; kt < 16; kt++) {
    const int cur = kt & 1, nxt = cur ^ 1;

    // ---- issue next-tile loads (order pinned: K-stage, bias, V) ----
    if (kt + 1 < 16) {
      STAGEK(nxt, kt + 1);
      __builtin_amdgcn_sched_barrier(0);
      const bf16_t* bb = bsrc + (kt + 1) * 64;
#pragma unroll
      for (int nf = 0; nf < 4; nf++) biasB[nf] = *(const bf16x4*)(bb + nf * 16);
      __builtin_amdgcn_sched_barrier(0);
    }
    if (kt + 2 < 16) {
      if (cur == 0) VLOAD(kt + 2, va0, va1);
      else          VLOAD(kt + 2, vb0, vb1);
      __builtin_amdgcn_sched_barrier(0);
    }
    if (kt + 1 < 16) {
      if (cur == 0) VSCAT(nxt, vb0, vb1);  // V(kt+1), loaded last iter
      else          VSCAT(nxt, va0, va1);
    }

    // ---- S^T = K Q^T : lane holds S[qrow][kp = 16nf + 4g + i] ----
    f32x4 sv[4];
    __builtin_amdgcn_s_setprio(1);
#pragma unroll
    for (int nf = 0; nf < 4; nf++) {
      const char* base = (const char*)Ks[cur] + (16 * nf + sl) * 128;
      bf16x8 kf0 = *(const bf16x8*)(base + ((g ^ (sl & 7)) * 16));
      bf16x8 kf1 = *(const bf16x8*)(base + (((4 + g) ^ (sl & 7)) * 16));
      f32x4 z = {0.f, 0.f, 0.f, 0.f};
      z = __builtin_amdgcn_mfma_f32_16x16x32_bf16(kf0, qf[0], z, 0, 0, 0);
      z = __builtin_amdgcn_mfma_f32_16x16x32_bf16(kf1, qf[1], z, 0, 0, 0);
      sv[nf] = z;
    }
    __builtin_amdgcn_s_setprio(0);

    // ---- logits (bias from registers, pre-scaled by log2e) ----
    float lg[4][4];
#pragma unroll
    for (int nf = 0; nf < 4; nf++)
#pragma unroll
      for (int i = 0; i < 4; i++)
        lg[nf][i] = fmaf(sv[nf][i], C1, (float)biasA[nf][i]);

    // ---- row max: in-reg tree + 2 shfls ----
    float mx = fmaxf(fmaxf(fmaxf(lg[0][0], lg[0][1]), fmaxf(lg[0][2], lg[0][3])),
                     fmaxf(fmaxf(lg[1][0], lg[1][1]), fmaxf(lg[1][2], lg[1][3])));
    mx = fmaxf(mx, fmaxf(fmaxf(fmaxf(lg[2][0], lg[2][1]), fmaxf(lg[2][2], lg[2][3])),
                         fmaxf(fmaxf(lg[3][0], lg[3][1]), fmaxf(lg[3][2], lg[3][3]))));
    mx = fmaxf(mx, __shfl_xor(mx, 16));
    mx = fmaxf(mx, __shfl_xor(mx, 32));

    // ---- defer-max rescale (T13) ----
    if (!__all(mx - m_run <= 8.0f)) {
      const float mnew = fmaxf(m_run, mx);
      const float alpha = exp2f(m_run - mnew);
      m_run = mnew;
      l_run *= alpha;
#pragma unroll
      for (int i = 0; i < 4; i++) {
        const float a_pv = __shfl(alpha, g * 4 + i);
#pragma unroll
        for (int nf2 = 0; nf2 < 4; nf2++) oacc[nf2][i] *= a_pv;
      }
    }

    // ---- exp + row sum ----
    float rs = 0.f;
#pragma unroll
    for (int nf = 0; nf < 4; nf++)
#pragma unroll
      for (int i = 0; i < 4; i++) {
        lg[nf][i] = exp2f(lg[nf][i] - m_run);
        rs += lg[nf][i];
      }
    rs += __shfl_xor(rs, 16);
    rs += __shfl_xor(rs, 32);
    l_run += rs;

    // ---- P -> per-wave LDS (packed b64, XOR-swizzled) ----
    bf16_t* Pw = Ps[w];
    {
      char* pb = (char*)Pw + sl * 128 + (g & 1) * 8;
#pragma unroll
      for (int nf = 0; nf < 4; nf++) {
        bf16x4 pk = {(bf16_t)lg[nf][0], (bf16_t)lg[nf][1], (bf16_t)lg[nf][2], (bf16_t)lg[nf][3]};
        *(bf16x4*)(pb + ((2 * nf + (g >> 1)) ^ (sl & 7)) * 16) = pk;
      }
    }
    bf16x8 pf[2];
#pragma unroll
    for (int c = 0; c < 2; c++)
      pf[c] = *(const bf16x8*)((char*)Pw + sl * 128 + ((4 * c + g) ^ (sl & 7)) * 16);

    // ---- O += P V ----
    __builtin_amdgcn_s_setprio(1);
#pragma unroll
    for (int nf2 = 0; nf2 < 4; nf2++) {
      const int d = nf2 * 16 + sl;
      const bf16_t* vb = Vt[cur] + d * 64;
      bf16x8 vf0 = *(const bf16x8*)(vb + ((g ^ (d & 7)) * 8));
      bf16x8 vf1 = *(const bf16x8*)(vb + (((g + 4) ^ (d & 7)) * 8));
      oacc[nf2] = __builtin_amdgcn_mfma_f32_16x16x32_bf16(pf[0], vf0, oacc[nf2], 0, 0, 0);
      oacc[nf2] = __builtin_amdgcn_mfma_f32_16x16x32_bf16(pf[1], vf1, oacc[nf2], 0, 0, 0);
    }
    __builtin_amdgcn_s_setprio(0);

    // ---- rotate bias prefetch; tile boundary ----
    if (kt + 1 < 16) {
#pragma unroll
      for (int nf = 0; nf < 4; nf++) biasA[nf] = biasB[nf];  // dep-waits bias(kt+1)
      asm volatile("s_waitcnt vmcnt(2) lgkmcnt(0)" ::: "memory");  // K(kt+1) landed; V stays in flight
      __builtin_amdgcn_s_barrier();
      __builtin_amdgcn_sched_barrier(0);
    }
  }

  // ---- normalize + store (C-layout: row q = g*4+i, col d = nf2*16+sl) ----
#pragma unroll
  for (int i = 0; i < 4; i++) {
    const float inv = 1.0f / __shfl(l_run, g * 4 + i);
    const size_t row = rowb + qt * 64 + w * 16 + g * 4 + i;
#pragma unroll
    for (int nf2 = 0; nf2 < 4; nf2++)
      o[row * 768 + h * 64 + nf2 * 16 + sl] = (bf16_t)(oacc[nf2][i] * inv);
  }
}

// ------------------------------- launcher ------------------------------------
extern "C" void kernel_launch(void* const* d_in, const int* in_sizes, int n_in,
                              void* d_out, int out_size, void* d_ws, size_t ws_size,
                              hipStream_t stream) {
  const float* x    = (const float*)d_in[0];
  const float* tin  = (const float*)d_in[1];
  const float* bias = (const float*)d_in[2];
  const float* Wxq  = (const float*)d_in[3];
  const float* Wxk  = (const float*)d_in[4];
  const float* Wxv  = (const float*)d_in[5];
  const float* Wtq  = (const float*)d_in[6];
  const float* Wtk  = (const float*)d_in[7];
  const float* Wtv  = (const float*)d_in[8];
  const float* Wo   = (const float*)d_in[9];
  const float* bo   = (const float*)d_in[10];
  float* out = (float*)d_out;

  char* ws = (char*)d_ws;
  bf16_t* x_bf    = (bf16_t*)(ws);                 // 12,582,912
  bf16_t* wcat    = (bf16_t*)(ws + 12582912);      //  3,538,944
  bf16_t* wo_bf   = (bf16_t*)(ws + 16121856);      //  1,179,648
  float*  shift   = (float*) (ws + 17301504);      //     73,728
  bf16_t* qkvb    = (bf16_t*)(ws + 17375232);      // 37,748,736
  bf16_t* obuf    = (bf16_t*)(ws + 55123968);      // 12,582,912
  bf16_t* bias_bf = (bf16_t*)(ws + 67706880);      // 25,165,824
  // total 92,872,704 bytes

  const int W = 768 * 768;
  cvt_f32_to_bf16<<<6144, 256, 0, stream>>>(x, x_bf, 8192 * 768);
  cvt_f32_to_bf16<<<576, 256, 0, stream>>>(Wxq, wcat, W);
  cvt_f32_to_bf16<<<576, 256, 0, stream>>>(Wxk, wcat + W, W);
  cvt_f32_to_bf16<<<576, 256, 0, stream>>>(Wxv, wcat + 2 * W, W);
  cvt_f32_to_bf16<<<576, 256, 0, stream>>>(Wo, wo_bf, W);
  cvt_scale_bf16<<<12288, 256, 0, stream>>>(bias, bias_bf, 12 * 1024 * 1024);
  shift_kernel<<<72, 256, 0, stream>>>(tin, Wtq, Wtk, Wtv, shift);
  gemm_bt<0><<<dim3(64, 18), 256, 0, stream>>>(x_bf, wcat, shift, qkvb, 8192, 2304, 768);
  attn_fused<<<1536, 256, 0, stream>>>(qkvb, bias_bf, obuf);
  gemm_bt<1><<<dim3(64, 6), 256, 0, stream>>>(obuf, wo_bf, bo, out, 8192, 768, 768);
}